// Round 1
// baseline (73.163 us; speedup 1.0000x reference)
//
#include <hip/hip_runtime.h>

#define BB 64
#define NN 307
#define HH 64
#define DD 768
#define EE 2456
#define ET 2763           // EE + NN self loops
#define MM (BB*NN)        // 19648
#define DEGMAX 128

// ---- ws layout (bytes) ----
#define XL_OFF   0u
#define XL_SZ    (MM*DD*2u)              // 30,179,328
#define XR_OFF   (XL_OFF + XL_SZ)
#define GSRC_OFF (XR_OFF + XL_SZ)        // [NN][DEGMAX] ints
#define GDEG_OFF (GSRC_OFF + NN*DEGMAX*4u)

typedef __attribute__((ext_vector_type(8))) short short8;
typedef __attribute__((ext_vector_type(4))) float f32x4;
typedef __attribute__((ext_vector_type(2))) float f32x2;
typedef __attribute__((ext_vector_type(4))) unsigned u32x4;
typedef __attribute__((ext_vector_type(2))) unsigned u32x2;

__device__ __forceinline__ unsigned short f2bf(float f){
  union{float f; unsigned u;} c; c.f=f;
  unsigned u=c.u;
  return (unsigned short)((u + 0x7fffu + ((u>>16)&1u))>>16);
}

// ---------- 1. fused MFMA bf16 GEMM (xl AND xr) + CSR, one dispatch -------
// grid (77, 6, 2): z=0 -> both GEMMs for 4 M-tiles (W staged ONCE per block);
//                  z=1 (y==0) -> CSR, one wave per node (4 nodes/block).
__global__ __launch_bounds__(256) void k_gemm(
    const float* __restrict__ z,
    const float* __restrict__ Wl, const float* __restrict__ bl,
    const float* __restrict__ Wr, const float* __restrict__ br,
    const int* __restrict__ r1, const int* __restrict__ r2,
    int* __restrict__ gdeg, int* __restrict__ gsrc,
    unsigned short* __restrict__ xl, unsigned short* __restrict__ xr)
{
  __shared__ unsigned short sBTl[128][72];  // Wl^T [col][k], padded (18 KB)
  __shared__ unsigned short sBTr[128][72];  // Wr^T [col][k], padded (18 KB)
  __shared__ unsigned short sC[64][136];    // epilogue staging, padded (17 KB)

  const int tid = threadIdx.x;
  const int lane = tid & 63, wv = tid >> 6;

  if (blockIdx.z == 1){
    // ---- CSR: one wave scans all ET edges for node n (ballot compaction) --
    if (blockIdx.y != 0) return;
    const int n = blockIdx.x*4 + wv;
    if (n >= NN) return;
    int cnt = 0;
    for (int base = 0; base < ET; base += 64){
      const int e = base + lane;
      int d = -1, s = 0;
      if (e < ET){
        if (e < EE){ d = r2[e]; s = r1[e]; }
        else       { d = e - EE; s = d; }
      }
      const bool hit = (d == n);
      unsigned long long mb = __ballot(hit);
      if (hit){
        int pos = cnt + (int)__popcll(mb & ((1ull << lane) - 1ull));
        if (pos < DEGMAX) gsrc[n*DEGMAX + pos] = s;
      }
      cnt += (int)__popcll(mb);
    }
    if (lane == 0) gdeg[n] = (cnt < DEGMAX) ? cnt : DEGMAX;
    return;
  }

  const int n0 = blockIdx.y*128;

  // stage BOTH W^T tiles (f32 -> bf16), coalesced — ONCE for 4 M-tiles
  #pragma unroll
  for (int it=0; it<32; it++){
    int idx = it*256 + tid;
    int k = idx >> 7, c = idx & 127;
    sBTl[c][k] = f2bf(Wl[(size_t)k*DD + n0 + c]);
    sBTr[c][k] = f2bf(Wr[(size_t)k*DD + n0 + c]);
  }
  __syncthreads();

  const int bcol = lane & 15;
  const int kp   = (lane >> 4) * 8;

  #pragma unroll 1
  for (int t=0; t<4; t++){
    const int tm = blockIdx.x*4 + t;
    if (tm >= MM/64) break;
    const int m0 = tm*64;

    // shared A fragments (one z read serves both GEMMs)
    const int arow = m0 + wv*16 + (lane & 15);
    const float* pz = z + (size_t)arow*HH + kp;
    float4 za0 = *(const float4*)(pz);
    float4 za1 = *(const float4*)(pz + 4);
    float4 zb0 = *(const float4*)(pz + 32);
    float4 zb1 = *(const float4*)(pz + 36);
    short8 a0, a1;
    a0[0]=(short)f2bf(za0.x); a0[1]=(short)f2bf(za0.y); a0[2]=(short)f2bf(za0.z); a0[3]=(short)f2bf(za0.w);
    a0[4]=(short)f2bf(za1.x); a0[5]=(short)f2bf(za1.y); a0[6]=(short)f2bf(za1.z); a0[7]=(short)f2bf(za1.w);
    a1[0]=(short)f2bf(zb0.x); a1[1]=(short)f2bf(zb0.y); a1[2]=(short)f2bf(zb0.z); a1[3]=(short)f2bf(zb0.w);
    a1[4]=(short)f2bf(zb1.x); a1[5]=(short)f2bf(zb1.y); a1[6]=(short)f2bf(zb1.z); a1[7]=(short)f2bf(zb1.w);

    f32x4 accl[8], accr[8];
    #pragma unroll
    for (int cb=0; cb<8; cb++){
      accl[cb][0]=0.f; accl[cb][1]=0.f; accl[cb][2]=0.f; accl[cb][3]=0.f;
      accr[cb][0]=0.f; accr[cb][1]=0.f; accr[cb][2]=0.f; accr[cb][3]=0.f;
    }

    #pragma unroll
    for (int cb=0; cb<8; cb++){
      short8 b0l = *(const short8*)&sBTl[cb*16 + bcol][kp];
      short8 b1l = *(const short8*)&sBTl[cb*16 + bcol][32 + kp];
      accl[cb] = __builtin_amdgcn_mfma_f32_16x16x32_bf16(a0, b0l, accl[cb], 0, 0, 0);
      accl[cb] = __builtin_amdgcn_mfma_f32_16x16x32_bf16(a1, b1l, accl[cb], 0, 0, 0);
      short8 b0r = *(const short8*)&sBTr[cb*16 + bcol][kp];
      short8 b1r = *(const short8*)&sBTr[cb*16 + bcol][32 + kp];
      accr[cb] = __builtin_amdgcn_mfma_f32_16x16x32_bf16(a0, b0r, accr[cb], 0, 0, 0);
      accr[cb] = __builtin_amdgcn_mfma_f32_16x16x32_bf16(a1, b1r, accr[cb], 0, 0, 0);
    }

    // epilogue xl
    #pragma unroll
    for (int cb=0; cb<8; cb++){
      int cc = cb*16 + bcol;
      float bb = bl[n0 + cc];
      #pragma unroll
      for (int r=0; r<4; r++){
        int rr = wv*16 + (lane>>4)*4 + r;
        sC[rr][cc] = f2bf(accl[cb][r] + bb);
      }
    }
    __syncthreads();
    #pragma unroll
    for (int it=0; it<4; it++){
      int idx = it*256 + tid;
      int rr = idx >> 4;
      int c8 = (idx & 15) * 8;
      uint4 v = *(const uint4*)&sC[rr][c8];
      *(uint4*)&xl[(size_t)(m0+rr)*DD + n0 + c8] = v;
    }
    __syncthreads();
    // epilogue xr
    #pragma unroll
    for (int cb=0; cb<8; cb++){
      int cc = cb*16 + bcol;
      float bb = br[n0 + cc];
      #pragma unroll
      for (int r=0; r<4; r++){
        int rr = wv*16 + (lane>>4)*4 + r;
        sC[rr][cc] = f2bf(accr[cb][r] + bb);
      }
    }
    __syncthreads();
    #pragma unroll
    for (int it=0; it<4; it++){
      int idx = it*256 + tid;
      int rr = idx >> 4;
      int c8 = (idx & 15) * 8;
      uint4 v = *(const uint4*)&sC[rr][c8];
      *(uint4*)&xr[(size_t)(m0+rr)*DD + n0 + c8] = v;
    }
    __syncthreads();   // protect sC reuse by next tile
  }
}

// ---------- 2. fused score + fixed-shift-softmax + aggregation ------------
// grid (64, 77); 256 threads = 4 INDEPENDENT waves (no LDS/barriers).
//   wave -> (n = blockIdx.y*4 + wv, b = blockIdx.x); lane owns 12 d-elems.
// STEP4: 4 edges/iter, 4 interleaved LDS-free DPP reductions (ror+bcast),
// score lands in SGPR via readlane; p = exp2(sc - C) (shift-invariant softmax,
// no online max); edge addressing via v_readlane of reg-resident src list
// (saddr global loads, no ds_bpermute); tails masked with p = 0.

#define BF_LO(u) __uint_as_float((u) << 16)
#define BF_HI(u) __uint_as_float((u) & 0xffff0000u)

template<int CTRL, int RM>
__device__ __forceinline__ float dpp_add(float v){
  int x = __builtin_amdgcn_update_dpp(0, __float_as_int(v), CTRL, RM, 0xf, true);
  return v + __int_as_float(x);
}
// 64-lane sum -> uniform scalar (SGPR). row_ror 1/2/4/8 makes every lane hold
// its 16-row sum; row_bcast:15 (rows 1,3) and row_bcast:31 (row 3) fold rows;
// lane 63 holds the total.
__device__ __forceinline__ float redux64u(float v){
  v = dpp_add<0x121,0xf>(v);   // row_ror:1
  v = dpp_add<0x122,0xf>(v);   // row_ror:2
  v = dpp_add<0x124,0xf>(v);   // row_ror:4
  v = dpp_add<0x128,0xf>(v);   // row_ror:8
  v = dpp_add<0x142,0xa>(v);   // row_bcast:15 -> rows 1,3
  v = dpp_add<0x143,0x8>(v);   // row_bcast:31 -> row 3
  return __uint_as_float((unsigned)__builtin_amdgcn_readlane(__float_as_int(v), 63));
}

#define LOAD6(DST, P) {                                           \
  u32x4 _u0 = *(const u32x4*)(P);                                 \
  u32x2 _u1 = *(const u32x2*)((P)+4);                             \
  DST[0]=_u0.x; DST[1]=_u0.y; DST[2]=_u0.z; DST[3]=_u0.w;         \
  DST[4]=_u1.x; DST[5]=_u1.y; }

// clamped edge pointer: scalar src id via v_readlane (uniform j) -> saddr load
#define EPTR(J) ({                                                \
  int _j = (J); int _jc = _j < degm1 ? _j : degm1;                \
  int _s = __builtin_amdgcn_readlane((_jc & 64) ? sv1 : sv0, _jc & 63); \
  (const unsigned*)(xlb + (size_t)_s*DD) + du; })

#define MKH(H, U) {                                               \
  _Pragma("unroll")                                               \
  for (int _t=0;_t<6;_t++){                                       \
    f32x2 _x; _x.x = BF_LO(U[_t]); _x.y = BF_HI(U[_t]);           \
    H[_t] = _x + xrf2[_t]; } }

#define SCORE_H(SC2, H) {                                         \
  _Pragma("unroll")                                               \
  for (int _t=0;_t<6;_t++){                                       \
    f32x2 _s = H[_t] * 0.2f;                                      \
    f32x2 _l;                                                     \
    _l.x = fmaxf(H[_t].x, _s.x);                                  \
    _l.y = fmaxf(H[_t].y, _s.y);                                  \
    SC2 += _l * attv2[_t]; } }

#define ACCH(P, H) {                                              \
  _Pragma("unroll")                                               \
  for (int _t=0;_t<6;_t++) acc2[_t] += (P) * H[_t]; }

__global__ __launch_bounds__(256) void k_fusedf(
    const unsigned short* __restrict__ xl, const unsigned short* __restrict__ xr,
    const int* __restrict__ gdeg, const int* __restrict__ gsrc,
    const float* __restrict__ att, const float* __restrict__ bias,
    float* __restrict__ out)
{
  const int b = blockIdx.x;
  const int wv = threadIdx.x >> 6;
  const int nv = blockIdx.y*4 + wv;
  if (nv >= NN) return;                    // no barriers/LDS -> safe
  const int n = __builtin_amdgcn_readfirstlane(nv);   // force SGPR addressing
  const int lane = threadIdx.x & 63;
  const int du = lane * 6;           // uint (2-elem) offset within the 768-row

  // src list -> 2 VGPRs (coalesced); per-edge broadcast via v_readlane
  int sv0 = gsrc[n*DEGMAX + lane];
  int sv1 = gsrc[n*DEGMAX + 64 + lane];
  const int deg = gdeg[n];           // >= 1 (self loop), uniform
  const int degm1 = deg - 1;

  f32x2 attv2[6], xrf2[6], acc2[6];
  {
    const f32x2* pa2 = (const f32x2*)(att + du*2);
    #pragma unroll
    for (int t=0;t<6;t++) attv2[t] = pa2[t] * 1.4426950408889634f; // fold log2e
    // xr row: one-shot read, non-temporal (don't evict xl gather set)
    const unsigned* px = (const unsigned*)(xr + ((size_t)b*NN + n)*DD) + du;
    u32x4 x0 = __builtin_nontemporal_load((const u32x4*)px);
    u32x2 x1 = __builtin_nontemporal_load((const u32x2*)(px+4));
    unsigned xx[6] = {x0.x, x0.y, x0.z, x0.w, x1.x, x1.y};
    #pragma unroll
    for (int t=0;t<6;t++){
      xrf2[t].x = BF_LO(xx[t]);
      xrf2[t].y = BF_HI(xx[t]);
    }
  }
  #pragma unroll
  for (int t=0;t<6;t++){ acc2[t].x = 0.f; acc2[t].y = 0.f; }

  const unsigned short* xlb = xl + (size_t)b*NN*DD;
  float ssum = 0.f;
  const float C2 = 11.5415603f;      // 8 * log2(e); softmax is shift-invariant

  // prologue: 4 edges in flight (clamped; invalid ones get p = 0 later)
  unsigned uA[6], uB[6], uC[6], uD[6];
  LOAD6(uA, EPTR(0)); LOAD6(uB, EPTR(1)); LOAD6(uC, EPTR(2)); LOAD6(uD, EPTR(3));

  for (int i = 0; i < deg; i += 4){
    f32x2 hA[6], hB[6], hC[6], hD[6];
    MKH(hA, uA); MKH(hB, uB); MKH(hC, uC); MKH(hD, uD);
    if (i + 4 < deg){                     // prefetch next group (uniform branch)
      LOAD6(uA, EPTR(i+4)); LOAD6(uB, EPTR(i+5));
      LOAD6(uC, EPTR(i+6)); LOAD6(uD, EPTR(i+7));
    }
    f32x2 s2A = {0.f,0.f}, s2B = {0.f,0.f}, s2C = {0.f,0.f}, s2D = {0.f,0.f};
    SCORE_H(s2A, hA); SCORE_H(s2B, hB); SCORE_H(s2C, hC); SCORE_H(s2D, hD);
    float sA = redux64u(s2A.x + s2A.y);   // 4 chains interleave, no LDS ops
    float sB = redux64u(s2B.x + s2B.y);
    float sCv = redux64u(s2C.x + s2C.y);
    float sD = redux64u(s2D.x + s2D.y);
    float p0 = __builtin_amdgcn_exp2f(sA - C2);
    float p1 = (i+1 < deg) ? __builtin_amdgcn_exp2f(sB - C2) : 0.f;
    float p2 = (i+2 < deg) ? __builtin_amdgcn_exp2f(sCv - C2) : 0.f;
    float p3 = (i+3 < deg) ? __builtin_amdgcn_exp2f(sD - C2) : 0.f;
    ssum += (p0 + p1) + (p2 + p3);
    ACCH(p0, hA); ACCH(p1, hB); ACCH(p2, hC); ACCH(p3, hD);
  }

  // out = acc_h/ssum - xr + bias   (since sum p*xr = ssum*xr); nt stores
  const float inv = 1.f / ssum;
  float* po = out + ((size_t)b*NN + n)*DD + du*2;
  const f32x2* pb2 = (const f32x2*)(bias + du*2);
  #pragma unroll
  for (int t=0;t<6;t+=2){
    f32x2 oa = acc2[t]   * inv + (pb2[t]   - xrf2[t]);
    f32x2 ob = acc2[t+1] * inv + (pb2[t+1] - xrf2[t+1]);
    f32x4 o4; o4[0]=oa.x; o4[1]=oa.y; o4[2]=ob.x; o4[3]=ob.y;
    __builtin_nontemporal_store(o4, (f32x4*)(po + 2*t));
  }
}

extern "C" void kernel_launch(void* const* d_in, const int* in_sizes, int n_in,
                              void* d_out, int out_size, void* d_ws, size_t ws_size,
                              hipStream_t stream)
{
  const float* z   = (const float*)d_in[1];
  const int*   r1  = (const int*)  d_in[2];
  const int*   r2  = (const int*)  d_in[3];
  const float* Wl  = (const float*)d_in[4];
  const float* bl  = (const float*)d_in[5];
  const float* Wr  = (const float*)d_in[6];
  const float* br  = (const float*)d_in[7];
  const float* att = (const float*)d_in[8];
  const float* bias= (const float*)d_in[9];
  float* out = (float*)d_out;

  char* ws = (char*)d_ws;
  unsigned short* xl = (unsigned short*)(ws + XL_OFF);
  unsigned short* xr = (unsigned short*)(ws + XR_OFF);
  int* gsrc = (int*)(ws + GSRC_OFF);
  int* gdeg = (int*)(ws + GDEG_OFF);

  k_gemm<<<dim3((MM/64 + 3)/4, DD/128, 2), 256, 0, stream>>>(z, Wl, bl, Wr, br,
                                                     r1, r2, gdeg, gsrc, xl, xr);
  k_fusedf<<<dim3(BB, (NN+3)/4), 256, 0, stream>>>(xl, xr, gdeg, gsrc, att, bias, out);
}